// Round 1
// baseline (13984.454 us; speedup 1.0000x reference)
//
#include <hip/hip_runtime.h>
#include <hip/hip_bf16.h>

// BiRNN: B=64, T=512, F=512, H=512, fp32 in/out.
// Kernel 1 (gemm_xw): xw = x@W + b (bf16 MFMA), staged directly into d_out
//   (fw at [b][t][0:512]; bw at [b][T-1-t][512:1024] so the recurrence reads
//   both directions in step order).
// Kernel 2 (rnn_rec): one WG per (dir, batch) chain; U held entirely in VGPRs
//   (768 threads x ~352 regs); h in LDS; 512 sequential steps, no inter-WG sync.

using bf16 = __hip_bfloat16;
typedef __attribute__((ext_vector_type(8))) short short8;   // bf16x8 MFMA frag
typedef __attribute__((ext_vector_type(4))) float float4v;  // fp32x4 acc

#define T_STEPS 512
#define HDIM    512

__global__ __launch_bounds__(256) void gemm_xw(
    const float* __restrict__ x,
    const float* __restrict__ Wf, const float* __restrict__ bf_,
    const float* __restrict__ Wb, const float* __restrict__ bb_,
    float* __restrict__ out)
{
    int bid = blockIdx.x;
    int dir = bid >> 12;          // 4096 blocks per direction
    int r   = bid & 4095;
    int mt  = r >> 3;             // 64-row tile of X (512 tiles)
    int nt  = r & 7;              // 64-col tile of W (8 tiles)
    const float* W    = dir ? Wb  : Wf;
    const float* bias = dir ? bb_ : bf_;

    __shared__ __align__(16) bf16 Xl[64][40];   // 64 rows x 32 k (pad->40)
    __shared__ __align__(16) bf16 Wt[64][40];   // 64 n    x 32 k (transposed)

    int tid  = threadIdx.x;
    int wave = tid >> 6;
    int lane = tid & 63;
    int lm   = lane & 15;
    int quad = lane >> 4;

    float4v acc[4];
    #pragma unroll
    for (int i = 0; i < 4; ++i) acc[i] = (float4v){0.f, 0.f, 0.f, 0.f};

    int row0 = mt * 64;
    int srow = tid >> 2;            // 0..63
    int sk8  = (tid & 3) * 8;       // 0,8,16,24
    int wrow = tid >> 3;            // 0..31
    int wn8  = (tid & 7) * 8;       // 0..56

    for (int kt = 0; kt < 16; ++kt) {
        int k0 = kt * 32;
        // stage X tile (fp32 -> bf16)
        const float* xp = x + (size_t)(row0 + srow) * 512 + k0 + sk8;
        float4v xa = *(const float4v*)xp;
        float4v xb = *(const float4v*)(xp + 4);
        union { short8 v; bf16 e[8]; } ux;
        ux.e[0] = __float2bfloat16(xa.x); ux.e[1] = __float2bfloat16(xa.y);
        ux.e[2] = __float2bfloat16(xa.z); ux.e[3] = __float2bfloat16(xa.w);
        ux.e[4] = __float2bfloat16(xb.x); ux.e[5] = __float2bfloat16(xb.y);
        ux.e[6] = __float2bfloat16(xb.z); ux.e[7] = __float2bfloat16(xb.w);
        *(short8*)&Xl[srow][sk8] = ux.v;
        // stage W tile transposed (fp32 -> bf16)
        const float* wp = W + (size_t)(k0 + wrow) * 512 + nt * 64 + wn8;
        float4v wa = *(const float4v*)wp;
        float4v wb = *(const float4v*)(wp + 4);
        Wt[wn8 + 0][wrow] = __float2bfloat16(wa.x);
        Wt[wn8 + 1][wrow] = __float2bfloat16(wa.y);
        Wt[wn8 + 2][wrow] = __float2bfloat16(wa.z);
        Wt[wn8 + 3][wrow] = __float2bfloat16(wa.w);
        Wt[wn8 + 4][wrow] = __float2bfloat16(wb.x);
        Wt[wn8 + 5][wrow] = __float2bfloat16(wb.y);
        Wt[wn8 + 6][wrow] = __float2bfloat16(wb.z);
        Wt[wn8 + 7][wrow] = __float2bfloat16(wb.w);
        __syncthreads();

        short8 a = *(const short8*)&Xl[wave * 16 + lm][quad * 8];
        #pragma unroll
        for (int n4 = 0; n4 < 4; ++n4) {
            short8 bfr = *(const short8*)&Wt[n4 * 16 + lm][quad * 8];
            acc[n4] = __builtin_amdgcn_mfma_f32_16x16x32_bf16(a, bfr, acc[n4], 0, 0, 0);
        }
        __syncthreads();
    }

    // epilogue: C/D layout col=lane&15, row=quad*4+reg  [m89-verified]
    #pragma unroll
    for (int n4 = 0; n4 < 4; ++n4) {
        int ncol = nt * 64 + n4 * 16 + lm;      // 0..511 within H
        float bv = bias[ncol];
        #pragma unroll
        for (int rr = 0; rr < 4; ++rr) {
            int m = wave * 16 + quad * 4 + rr;
            int g = row0 + m;                   // global X row
            int b = g >> 9;
            int t = g & 511;
            int tp = dir ? (511 - t) : t;       // bw: step order = reversed time
            out[((size_t)b * T_STEPS + tp) * 1024 + dir * 512 + ncol] = acc[n4][rr] + bv;
        }
    }
}

__global__ __launch_bounds__(768, 1) void rnn_rec(
    const float* __restrict__ Uf, const float* __restrict__ Ub,
    float* __restrict__ out)
{
    int dir = blockIdx.x >> 6;
    int b   = blockIdx.x & 63;
    const float* U = dir ? Ub : Uf;
    float* obase = out + (size_t)b * T_STEPS * 1024 + dir * 512;

    int tid = threadIdx.x;
    int j   = tid >> 8;      // k-third: 0,1,2  (k ranges 176/176/160+pad)
    int cq  = tid & 255;     // column pair
    int c0  = cq * 2;

    __shared__ __align__(16) float hbuf[528];     // h state (512) + zero pad
    __shared__ float pbuf[3][512];                // partial sums per k-third

    for (int i = tid; i < 528; i += 768) hbuf[i] = 0.f;

    // Load U into registers: k in [j*176, j*176+176), cols c0,c0+1.
    // k >= 512 (only j==2 tail): address clamped; contributes 0 since hbuf pad is 0.
    float4v U0[44], U1[44];
    int kbase = j * 176;
    #pragma unroll
    for (int i = 0; i < 44; ++i) {
        float2 e[4];
        #pragma unroll
        for (int q = 0; q < 4; ++q) {
            int k  = kbase + i * 4 + q;
            int kc = k < 512 ? k : 511;
            e[q] = *(const float2*)(U + (size_t)kc * 512 + c0);
        }
        U0[i] = (float4v){e[0].x, e[1].x, e[2].x, e[3].x};
        U1[i] = (float4v){e[0].y, e[1].y, e[2].y, e[3].y};
    }
    __syncthreads();

    const float4v* hb4 = (const float4v*)hbuf;
    int hbase = j * 44;

    #pragma unroll 1
    for (int t = 0; t < T_STEPS; ++t) {
        float* orow = obase + (size_t)t * 1024 + c0;
        float2 xw = make_float2(0.f, 0.f);
        if (j == 0) xw = *(const float2*)orow;      // prefetch xw_t (staged by gemm_xw)

        float4v a0 = (float4v){0.f, 0.f, 0.f, 0.f};
        float4v a1 = (float4v){0.f, 0.f, 0.f, 0.f};
        #pragma unroll
        for (int i = 0; i < 44; ++i) {
            float4v h4 = hb4[hbase + i];
            a0 += h4 * U0[i];
            a1 += h4 * U1[i];
        }
        float s0 = (a0.x + a0.y) + (a0.z + a0.w);
        float s1 = (a1.x + a1.y) + (a1.z + a1.w);
        *(float2*)&pbuf[j][c0] = make_float2(s0, s1);
        __syncthreads();

        if (j == 0) {
            float2 p1 = *(const float2*)&pbuf[1][c0];
            float2 p2 = *(const float2*)&pbuf[2][c0];
            float h0 = tanhf(s0 + p1.x + p2.x + xw.x);
            float h1 = tanhf(s1 + p1.y + p2.y + xw.y);
            *(float2*)orow = make_float2(h0, h1);          // final output
            *(float2*)&hbuf[c0] = make_float2(h0, h1);     // next-step state
        }
        __syncthreads();
    }
}

extern "C" void kernel_launch(void* const* d_in, const int* in_sizes, int n_in,
                              void* d_out, int out_size, void* d_ws, size_t ws_size,
                              hipStream_t stream) {
    const float* x   = (const float*)d_in[0];
    const float* Wf  = (const float*)d_in[1];
    const float* Uf  = (const float*)d_in[2];
    const float* bf_ = (const float*)d_in[3];
    const float* Wb  = (const float*)d_in[4];
    const float* Ub  = (const float*)d_in[5];
    const float* bb_ = (const float*)d_in[6];
    float* out = (float*)d_out;

    hipLaunchKernelGGL(gemm_xw, dim3(8192), dim3(256), 0, stream,
                       x, Wf, bf_, Wb, bb_, out);
    hipLaunchKernelGGL(rnn_rec, dim3(128), dim3(768), 0, stream,
                       Uf, Ub, out);
}

// Round 2
// 5185.480 us; speedup vs baseline: 2.6968x; 2.6968x over previous
//
#include <hip/hip_runtime.h>
#include <hip/hip_bf16.h>

// BiRNN: B=64, T=512, F=H=512, fp32 in/out.
// Kernel 1 (gemm_xw): xw = x@W + b (bf16 MFMA), staged into d_out
//   (fw at [b][t][0:512]; bw at [b][511-t][512:1024] => recurrence reads both
//   directions in step order).
// Kernel 2 (rnn_rec): recurrence batched over all 64 chains as per-step MFMA
//   GEMM H[64x512]@U[512x512]. 16 WGs per direction, each owns 32 U-columns
//   in LDS as split-bf16 (hi+lo => ~fp32 accuracy). H double-buffered in d_ws
//   (split-bf16 planes); per-step 16-way device-scope counter barrier.

using bf16 = __hip_bfloat16;
typedef __attribute__((ext_vector_type(8))) short short8;   // bf16x8 MFMA frag
typedef __attribute__((ext_vector_type(4))) float float4v;  // fp32x4 acc

#define T_STEPS 512
#define NWG     16      // WGs per direction
#define NCOL    32      // U columns per WG

// d_ws layout: [0..255]  ctr[dir] at byte dir*128
//              [1024..]  Hbuf bf16: per dir 131072 elems =
//                        2 phases x (hi plane 32768 + lo plane 32768)
#define HB_OFF  1024
#define WS_ZERO_BYTES (HB_OFF + 2 * 131072 * 2)   // 525,312 B

__global__ __launch_bounds__(256) void gemm_xw(
    const float* __restrict__ x,
    const float* __restrict__ Wf, const float* __restrict__ bf_,
    const float* __restrict__ Wb, const float* __restrict__ bb_,
    float* __restrict__ out)
{
    int bid = blockIdx.x;
    int dir = bid >> 12;          // 4096 blocks per direction
    int r   = bid & 4095;
    int mt  = r >> 3;             // 64-row tile of X (512 tiles)
    int nt  = r & 7;              // 64-col tile of W (8 tiles)
    const float* W    = dir ? Wb  : Wf;
    const float* bias = dir ? bb_ : bf_;

    __shared__ __align__(16) bf16 Xl[64][40];   // 64 rows x 32 k (pad->40)
    __shared__ __align__(16) bf16 Wt[64][40];   // 64 n    x 32 k (transposed)

    int tid  = threadIdx.x;
    int wave = tid >> 6;
    int lane = tid & 63;
    int lm   = lane & 15;
    int quad = lane >> 4;

    float4v acc[4];
    #pragma unroll
    for (int i = 0; i < 4; ++i) acc[i] = (float4v){0.f, 0.f, 0.f, 0.f};

    int row0 = mt * 64;
    int srow = tid >> 2;            // 0..63
    int sk8  = (tid & 3) * 8;       // 0,8,16,24
    int wrow = tid >> 3;            // 0..31
    int wn8  = (tid & 7) * 8;       // 0..56

    for (int kt = 0; kt < 16; ++kt) {
        int k0 = kt * 32;
        const float* xp = x + (size_t)(row0 + srow) * 512 + k0 + sk8;
        float4v xa = *(const float4v*)xp;
        float4v xb = *(const float4v*)(xp + 4);
        union { short8 v; bf16 e[8]; } ux;
        ux.e[0] = __float2bfloat16(xa.x); ux.e[1] = __float2bfloat16(xa.y);
        ux.e[2] = __float2bfloat16(xa.z); ux.e[3] = __float2bfloat16(xa.w);
        ux.e[4] = __float2bfloat16(xb.x); ux.e[5] = __float2bfloat16(xb.y);
        ux.e[6] = __float2bfloat16(xb.z); ux.e[7] = __float2bfloat16(xb.w);
        *(short8*)&Xl[srow][sk8] = ux.v;
        const float* wp = W + (size_t)(k0 + wrow) * 512 + nt * 64 + wn8;
        float4v wa = *(const float4v*)wp;
        float4v wb = *(const float4v*)(wp + 4);
        Wt[wn8 + 0][wrow] = __float2bfloat16(wa.x);
        Wt[wn8 + 1][wrow] = __float2bfloat16(wa.y);
        Wt[wn8 + 2][wrow] = __float2bfloat16(wa.z);
        Wt[wn8 + 3][wrow] = __float2bfloat16(wa.w);
        Wt[wn8 + 4][wrow] = __float2bfloat16(wb.x);
        Wt[wn8 + 5][wrow] = __float2bfloat16(wb.y);
        Wt[wn8 + 6][wrow] = __float2bfloat16(wb.z);
        Wt[wn8 + 7][wrow] = __float2bfloat16(wb.w);
        __syncthreads();

        short8 a = *(const short8*)&Xl[wave * 16 + lm][quad * 8];
        #pragma unroll
        for (int n4 = 0; n4 < 4; ++n4) {
            short8 bfr = *(const short8*)&Wt[n4 * 16 + lm][quad * 8];
            acc[n4] = __builtin_amdgcn_mfma_f32_16x16x32_bf16(a, bfr, acc[n4], 0, 0, 0);
        }
        __syncthreads();
    }

    // epilogue: C/D layout col=lane&15, row=quad*4+reg  [m89-verified]
    #pragma unroll
    for (int n4 = 0; n4 < 4; ++n4) {
        int ncol = nt * 64 + n4 * 16 + lm;
        float bv = bias[ncol];
        #pragma unroll
        for (int rr = 0; rr < 4; ++rr) {
            int m = wave * 16 + quad * 4 + rr;
            int g = row0 + m;
            int b = g >> 9;
            int t = g & 511;
            int tp = dir ? (511 - t) : t;       // bw: step order = reversed time
            out[((size_t)b * T_STEPS + tp) * 1024 + dir * 512 + ncol] = acc[n4][rr] + bv;
        }
    }
}

__global__ __launch_bounds__(256, 1) void rnn_rec(
    const float* __restrict__ Uf, const float* __restrict__ Ub,
    float* __restrict__ out, unsigned char* __restrict__ ws)
{
    unsigned* ctrs = (unsigned*)ws;               // ctr[dir] at byte dir*128
    bf16* Hbuf = (bf16*)(ws + HB_OFF);

    int wg  = blockIdx.x;                         // 0..31
    int dir = wg & 1;                             // interleave dirs across XCDs
    int g   = wg >> 1;                            // 0..15
    int n0  = g * NCOL;
    const float* U = dir ? Ub : Uf;

    int tid  = threadIdx.x;
    int wave = tid >> 6;
    int lane = tid & 63;
    int lm   = lane & 15;
    int quad = lane >> 4;
    int m0   = wave * 16;                         // 16 batch rows per wave

    // U column slice, split-bf16, transposed [n][k], k-pad 512->520 (2-way banks)
    __shared__ __align__(16) bf16 Uh[NCOL][520];
    __shared__ __align__(16) bf16 Ulo[NCOL][520];

    #pragma unroll
    for (int it = 0; it < 16; ++it) {
        int idx = it * 256 + tid;                 // 0..4095
        int k   = idx >> 3;
        int c   = (idx & 7) * 4;
        float4v v = *(const float4v*)(U + (size_t)k * 512 + n0 + c);
        #pragma unroll
        for (int q = 0; q < 4; ++q) {
            float f  = v[q];
            bf16 hi  = __float2bfloat16(f);
            float lo = f - __bfloat162float(hi);
            Uh[c + q][k]  = hi;
            Ulo[c + q][k] = __float2bfloat16(lo);
        }
    }
    __syncthreads();

    unsigned* myctr = ctrs + dir * 32;            // 128 B apart
    const size_t dbase = (size_t)dir * 131072;    // per-dir Hbuf elems
    float* obase = out + dir * 512;

    for (int t = 0; t < T_STEPS; ++t) {
        const bf16* Hh = Hbuf + dbase + (size_t)(t & 1) * 65536;
        const bf16* Hl = Hh + 32768;
        bf16* Wh = Hbuf + dbase + (size_t)((t + 1) & 1) * 65536;
        bf16* Wl = Wh + 32768;

        // prefetch xw for this step (written by gemm_xw; only we touch these cols)
        float xw[2][4];
        #pragma unroll
        for (int nf = 0; nf < 2; ++nf)
            #pragma unroll
            for (int r = 0; r < 4; ++r) {
                int b   = m0 + quad * 4 + r;
                int col = n0 + nf * 16 + lm;
                xw[nf][r] = obase[((size_t)b * T_STEPS + t) * 1024 + col];
            }

        // H[64x512] @ U[:, n0:n0+32] with split-bf16: hh@Uh + hl@Uh + hh@Ul
        float4v a0a = {0,0,0,0}, a0b = {0,0,0,0}, a0c = {0,0,0,0};
        float4v a1a = {0,0,0,0}, a1b = {0,0,0,0}, a1c = {0,0,0,0};
        #pragma unroll 4
        for (int kt = 0; kt < 16; ++kt) {
            int ko = kt * 32 + quad * 8;
            short8 ah  = *(const short8*)(Hh + (size_t)(m0 + lm) * 512 + ko);
            short8 al  = *(const short8*)(Hl + (size_t)(m0 + lm) * 512 + ko);
            short8 b0h = *(const short8*)&Uh[lm][ko];
            short8 b1h = *(const short8*)&Uh[16 + lm][ko];
            short8 b0l = *(const short8*)&Ulo[lm][ko];
            short8 b1l = *(const short8*)&Ulo[16 + lm][ko];
            a0a = __builtin_amdgcn_mfma_f32_16x16x32_bf16(ah, b0h, a0a, 0, 0, 0);
            a1a = __builtin_amdgcn_mfma_f32_16x16x32_bf16(ah, b1h, a1a, 0, 0, 0);
            a0b = __builtin_amdgcn_mfma_f32_16x16x32_bf16(al, b0h, a0b, 0, 0, 0);
            a1b = __builtin_amdgcn_mfma_f32_16x16x32_bf16(al, b1h, a1b, 0, 0, 0);
            a0c = __builtin_amdgcn_mfma_f32_16x16x32_bf16(ah, b0l, a0c, 0, 0, 0);
            a1c = __builtin_amdgcn_mfma_f32_16x16x32_bf16(ah, b1l, a1c, 0, 0, 0);
        }

        // epilogue: C/D col=lm, row=quad*4+r
        #pragma unroll
        for (int nf = 0; nf < 2; ++nf) {
            float4v s = nf ? (a1a + a1b + a1c) : (a0a + a0b + a0c);
            #pragma unroll
            for (int r = 0; r < 4; ++r) {
                int b   = m0 + quad * 4 + r;
                int col = n0 + nf * 16 + lm;
                float h = tanhf(s[r] + xw[nf][r]);
                obase[((size_t)b * T_STEPS + t) * 1024 + col] = h;
                bf16 hh = __float2bfloat16(h);
                Wh[(size_t)b * 512 + col] = hh;
                Wl[(size_t)b * 512 + col] = __float2bfloat16(h - __bfloat162float(hh));
            }
        }

        // 16-way per-direction device barrier (monotonic counter)
        __syncthreads();                          // all waves' writes drained
        if (tid == 0) {
            __threadfence();                      // release: H slice visible device-wide
            atomicAdd(myctr, 1u);
            unsigned tgt = (unsigned)(NWG * (t + 1));
            while (__hip_atomic_load(myctr, __ATOMIC_RELAXED,
                                     __HIP_MEMORY_SCOPE_AGENT) < tgt)
                __builtin_amdgcn_s_sleep(2);
        }
        __syncthreads();
        __threadfence();                          // acquire: see others' H slices
    }
}

extern "C" void kernel_launch(void* const* d_in, const int* in_sizes, int n_in,
                              void* d_out, int out_size, void* d_ws, size_t ws_size,
                              hipStream_t stream) {
    const float* x   = (const float*)d_in[0];
    const float* Wf  = (const float*)d_in[1];
    const float* Uf  = (const float*)d_in[2];
    const float* bf_ = (const float*)d_in[3];
    const float* Wb  = (const float*)d_in[4];
    const float* Ub  = (const float*)d_in[5];
    const float* bb_ = (const float*)d_in[6];
    float* out = (float*)d_out;

    hipMemsetAsync(d_ws, 0, WS_ZERO_BYTES, stream);   // ctr=0, H phase0 = 0
    hipLaunchKernelGGL(gemm_xw, dim3(8192), dim3(256), 0, stream,
                       x, Wf, bf_, Wb, bb_, out);
    hipLaunchKernelGGL(rnn_rec, dim3(32), dim3(256), 0, stream,
                       Uf, Ub, out, (unsigned char*)d_ws);
}

// Round 3
// 5076.926 us; speedup vs baseline: 2.7545x; 1.0214x over previous
//
#include <hip/hip_runtime.h>
#include <hip/hip_bf16.h>

// BiRNN: B=64, T=512, F=H=512, fp32 in/out.
// gemm_xw: xw = x@W + b (bf16 MFMA) staged into d_out (fw @[b][t][0:512],
//   bw @[b][511-t][512:1024]); XCD-swizzled so x-tiles are L2-shared.
// rnn_rec: per-step H[64x512]@U[512x512] via MFMA; 16 WGs/dir each own 32 U
//   cols in LDS (split-bf16). H exchanged through Infinity Cache with
//   agent-scope relaxed atomics (sc0 sc1 cache bypass) -- NO threadfence, so
//   no per-step L2 writeback/invalidate. H cols permuted so hi/lo bf16 pairs
//   pack into dwords; U k-rows use the same permutation (GEMM invariant).

using bf16 = __hip_bfloat16;
typedef __attribute__((ext_vector_type(8))) short short8;   // bf16x8 MFMA frag
typedef __attribute__((ext_vector_type(4))) float float4v;  // fp32x4 acc

#define T_STEPS 512
#define NWG     16      // WGs per direction
#define NCOL    32      // U columns per WG

// d_ws: [0..255] ctr[dir] at byte dir*128
//       [1024..] Hbuf u16: per dir 131072 elems = 2 phases x (hi 32768 + lo 32768)
#define HB_OFF  1024
#define WS_ZERO_BYTES (HB_OFF + 2 * 131072 * 2)

__device__ __forceinline__ unsigned short f2bf(float f) {
    unsigned u = __builtin_bit_cast(unsigned, f);
    u = (u + 0x7fffu + ((u >> 16) & 1u)) >> 16;
    return (unsigned short)u;
}
__device__ __forceinline__ float bf2f(unsigned short s) {
    unsigned u = ((unsigned)s) << 16;
    return __builtin_bit_cast(float, u);
}

__global__ __launch_bounds__(256) void gemm_xw(
    const float* __restrict__ x,
    const float* __restrict__ Wf, const float* __restrict__ bf_,
    const float* __restrict__ Wb, const float* __restrict__ bb_,
    float* __restrict__ out)
{
    int bid = blockIdx.x;
    int dir = bid >> 12;
    int r   = bid & 4095;
    // XCD swizzle: 64-block groups cover 8 mts x 8 nts; all nt-variants of an
    // mt share blockIdx%8 (same XCD) and are temporally adjacent.
    int i   = r & 63;
    int G   = r >> 6;
    int mt  = G * 8 + (i & 7);    // 0..511
    int nt  = i >> 3;             // 0..7
    const float* W    = dir ? Wb  : Wf;
    const float* bias = dir ? bb_ : bf_;

    __shared__ __align__(16) bf16 Xl[64][40];
    __shared__ __align__(16) bf16 Wt[64][40];

    int tid  = threadIdx.x;
    int wave = tid >> 6;
    int lane = tid & 63;
    int lm   = lane & 15;
    int quad = lane >> 4;

    float4v acc[4];
    #pragma unroll
    for (int q = 0; q < 4; ++q) acc[q] = (float4v){0.f, 0.f, 0.f, 0.f};

    int row0 = mt * 64;
    int srow = tid >> 2;
    int sk8  = (tid & 3) * 8;
    int wrow = tid >> 3;
    int wn8  = (tid & 7) * 8;

    for (int kt = 0; kt < 16; ++kt) {
        int k0 = kt * 32;
        const float* xp = x + (size_t)(row0 + srow) * 512 + k0 + sk8;
        float4v xa = *(const float4v*)xp;
        float4v xb = *(const float4v*)(xp + 4);
        union { short8 v; bf16 e[8]; } ux;
        ux.e[0] = __float2bfloat16(xa.x); ux.e[1] = __float2bfloat16(xa.y);
        ux.e[2] = __float2bfloat16(xa.z); ux.e[3] = __float2bfloat16(xa.w);
        ux.e[4] = __float2bfloat16(xb.x); ux.e[5] = __float2bfloat16(xb.y);
        ux.e[6] = __float2bfloat16(xb.z); ux.e[7] = __float2bfloat16(xb.w);
        *(short8*)&Xl[srow][sk8] = ux.v;
        const float* wp = W + (size_t)(k0 + wrow) * 512 + nt * 64 + wn8;
        float4v wa = *(const float4v*)wp;
        float4v wb = *(const float4v*)(wp + 4);
        Wt[wn8 + 0][wrow] = __float2bfloat16(wa.x);
        Wt[wn8 + 1][wrow] = __float2bfloat16(wa.y);
        Wt[wn8 + 2][wrow] = __float2bfloat16(wa.z);
        Wt[wn8 + 3][wrow] = __float2bfloat16(wa.w);
        Wt[wn8 + 4][wrow] = __float2bfloat16(wb.x);
        Wt[wn8 + 5][wrow] = __float2bfloat16(wb.y);
        Wt[wn8 + 6][wrow] = __float2bfloat16(wb.z);
        Wt[wn8 + 7][wrow] = __float2bfloat16(wb.w);
        __syncthreads();

        short8 a = *(const short8*)&Xl[wave * 16 + lm][quad * 8];
        #pragma unroll
        for (int n4 = 0; n4 < 4; ++n4) {
            short8 bfr = *(const short8*)&Wt[n4 * 16 + lm][quad * 8];
            acc[n4] = __builtin_amdgcn_mfma_f32_16x16x32_bf16(a, bfr, acc[n4], 0, 0, 0);
        }
        __syncthreads();
    }

    #pragma unroll
    for (int n4 = 0; n4 < 4; ++n4) {
        int ncol = nt * 64 + n4 * 16 + lm;
        float bv = bias[ncol];
        #pragma unroll
        for (int rr = 0; rr < 4; ++rr) {
            int m = wave * 16 + quad * 4 + rr;
            int g = row0 + m;
            int b = g >> 9;
            int t = g & 511;
            int tp = dir ? (511 - t) : t;
            out[((size_t)b * T_STEPS + tp) * 1024 + dir * 512 + ncol] = acc[n4][rr] + bv;
        }
    }
}

__global__ __launch_bounds__(256, 1) void rnn_rec(
    const float* __restrict__ Uf, const float* __restrict__ Ub,
    float* __restrict__ out, unsigned char* __restrict__ ws)
{
    unsigned* ctrs = (unsigned*)ws;
    unsigned short* Hbuf = (unsigned short*)(ws + HB_OFF);

    int wg  = blockIdx.x;          // 0..31
    int dir = wg & 1;
    int g   = wg >> 1;             // 0..15
    int n0  = g * NCOL;
    const float* U = dir ? Ub : Uf;

    int tid  = threadIdx.x;
    int wave = tid >> 6;
    int lane = tid & 63;
    int lm   = lane & 15;
    int quad = lane >> 4;
    int m0   = wave * 16;

    // U slice [n][pk]: k-rows under permutation p(k)=2(k&15)+((k>>4)&1)+32(k>>5)
    __shared__ __align__(16) unsigned short Uh[NCOL][520];
    __shared__ __align__(16) unsigned short Ulo[NCOL][520];

    #pragma unroll
    for (int it = 0; it < 16; ++it) {
        int idx = it * 256 + tid;               // 0..4095
        int k   = idx >> 3;
        int c   = (idx & 7) * 4;
        int pk  = ((k & 15) << 1) | ((k >> 4) & 1) | ((k >> 5) << 5);
        float4v v = *(const float4v*)(U + (size_t)k * 512 + n0 + c);
        #pragma unroll
        for (int q = 0; q < 4; ++q) {
            float f = v[q];
            unsigned short hi = f2bf(f);
            Uh[c + q][pk]  = hi;
            Ulo[c + q][pk] = f2bf(f - bf2f(hi));
        }
    }
    __syncthreads();

    unsigned* myctr = ctrs + dir * 32;          // 128 B apart
    const size_t dbase = (size_t)dir * 131072;
    float* obase = out + dir * 512;

    // xw prefetch for t=0
    float xw[2][4];
    #pragma unroll
    for (int nf = 0; nf < 2; ++nf)
        #pragma unroll
        for (int r = 0; r < 4; ++r) {
            int b   = m0 + quad * 4 + r;
            int col = n0 + nf * 16 + lm;
            xw[nf][r] = obase[((size_t)b * T_STEPS + 0) * 1024 + col];
        }

    int pc = g * 32 + 2 * lm;                   // physical col base (nf=0)

    for (int t = 0; t < T_STEPS; ++t) {
        unsigned short* Hh = Hbuf + dbase + (size_t)(t & 1) * 65536;
        unsigned short* Hl = Hh + 32768;
        unsigned short* Wh = Hbuf + dbase + (size_t)((t + 1) & 1) * 65536;
        unsigned short* Wl = Wh + 32768;

        // H[64x512] @ U[:,slice], split-bf16: ah@Uh + al@Uh + ah@Ul
        float4v a0a = {0,0,0,0}, a0b = {0,0,0,0}, a0c = {0,0,0,0};
        float4v a1a = {0,0,0,0}, a1b = {0,0,0,0}, a1c = {0,0,0,0};
        #pragma unroll 4
        for (int kt = 0; kt < 16; ++kt) {
            int ko = kt * 32 + quad * 8;        // physical k offset
            unsigned long long* pa = (unsigned long long*)(Hh + (size_t)(m0 + lm) * 512 + ko);
            unsigned long long* pl = (unsigned long long*)(Hl + (size_t)(m0 + lm) * 512 + ko);
            union { unsigned long long q[2]; short8 s; } ua, ul;
            ua.q[0] = __hip_atomic_load(pa,     __ATOMIC_RELAXED, __HIP_MEMORY_SCOPE_AGENT);
            ua.q[1] = __hip_atomic_load(pa + 1, __ATOMIC_RELAXED, __HIP_MEMORY_SCOPE_AGENT);
            ul.q[0] = __hip_atomic_load(pl,     __ATOMIC_RELAXED, __HIP_MEMORY_SCOPE_AGENT);
            ul.q[1] = __hip_atomic_load(pl + 1, __ATOMIC_RELAXED, __HIP_MEMORY_SCOPE_AGENT);
            short8 b0h = *(const short8*)&Uh[lm][ko];
            short8 b1h = *(const short8*)&Uh[16 + lm][ko];
            short8 b0l = *(const short8*)&Ulo[lm][ko];
            short8 b1l = *(const short8*)&Ulo[16 + lm][ko];
            a0a = __builtin_amdgcn_mfma_f32_16x16x32_bf16(ua.s, b0h, a0a, 0, 0, 0);
            a1a = __builtin_amdgcn_mfma_f32_16x16x32_bf16(ua.s, b1h, a1a, 0, 0, 0);
            a0b = __builtin_amdgcn_mfma_f32_16x16x32_bf16(ul.s, b0h, a0b, 0, 0, 0);
            a1b = __builtin_amdgcn_mfma_f32_16x16x32_bf16(ul.s, b1h, a1b, 0, 0, 0);
            a0c = __builtin_amdgcn_mfma_f32_16x16x32_bf16(ua.s, b0l, a0c, 0, 0, 0);
            a1c = __builtin_amdgcn_mfma_f32_16x16x32_bf16(ua.s, b1l, a1c, 0, 0, 0);
        }

        // epilogue: C/D col=lm, row=quad*4+r
        float hv[2][4];
        #pragma unroll
        for (int nf = 0; nf < 2; ++nf) {
            float4v s = nf ? (a1a + a1b + a1c) : (a0a + a0b + a0c);
            #pragma unroll
            for (int r = 0; r < 4; ++r) {
                int b   = m0 + quad * 4 + r;
                int col = n0 + nf * 16 + lm;
                float h = tanhf(s[r] + xw[nf][r]);
                hv[nf][r] = h;
                obase[((size_t)b * T_STEPS + t) * 1024 + col] = h;
            }
        }
        // H store: packed dwords, cache-bypassing (agent atomics -> LLC)
        #pragma unroll
        for (int r = 0; r < 4; ++r) {
            int b = m0 + quad * 4 + r;
            unsigned short h0 = f2bf(hv[0][r]);
            unsigned short h1 = f2bf(hv[1][r]);
            unsigned hi = (unsigned)h0 | ((unsigned)h1 << 16);
            unsigned short l0 = f2bf(hv[0][r] - bf2f(h0));
            unsigned short l1 = f2bf(hv[1][r] - bf2f(h1));
            unsigned lo = (unsigned)l0 | ((unsigned)l1 << 16);
            __hip_atomic_store((unsigned*)(Wh + (size_t)b * 512 + pc), hi,
                               __ATOMIC_RELAXED, __HIP_MEMORY_SCOPE_AGENT);
            __hip_atomic_store((unsigned*)(Wl + (size_t)b * 512 + pc), lo,
                               __ATOMIC_RELAXED, __HIP_MEMORY_SCOPE_AGENT);
        }

        // barrier: syncthreads drains vmcnt(0) => bypassing stores are at LLC
        __syncthreads();
        unsigned tgt = (unsigned)(NWG * (t + 1));
        if (tid == 0)
            __hip_atomic_fetch_add(myctr, 1u, __ATOMIC_RELAXED, __HIP_MEMORY_SCOPE_AGENT);

        // prefetch next step's xw (independent of barrier) while waiting
        int tn = (t + 1 < T_STEPS) ? (t + 1) : t;
        float xwn[2][4];
        #pragma unroll
        for (int nf = 0; nf < 2; ++nf)
            #pragma unroll
            for (int r = 0; r < 4; ++r) {
                int b   = m0 + quad * 4 + r;
                int col = n0 + nf * 16 + lm;
                xwn[nf][r] = obase[((size_t)b * T_STEPS + tn) * 1024 + col];
            }

        if (tid == 0) {
            while (__hip_atomic_load(myctr, __ATOMIC_RELAXED,
                                     __HIP_MEMORY_SCOPE_AGENT) < tgt)
                __builtin_amdgcn_s_sleep(2);
        }
        __syncthreads();

        #pragma unroll
        for (int nf = 0; nf < 2; ++nf)
            #pragma unroll
            for (int r = 0; r < 4; ++r) xw[nf][r] = xwn[nf][r];
    }
}

extern "C" void kernel_launch(void* const* d_in, const int* in_sizes, int n_in,
                              void* d_out, int out_size, void* d_ws, size_t ws_size,
                              hipStream_t stream) {
    const float* x   = (const float*)d_in[0];
    const float* Wf  = (const float*)d_in[1];
    const float* Uf  = (const float*)d_in[2];
    const float* bf_ = (const float*)d_in[3];
    const float* Wb  = (const float*)d_in[4];
    const float* Ub  = (const float*)d_in[5];
    const float* bb_ = (const float*)d_in[6];
    float* out = (float*)d_out;

    hipMemsetAsync(d_ws, 0, WS_ZERO_BYTES, stream);
    hipLaunchKernelGGL(gemm_xw, dim3(8192), dim3(256), 0, stream,
                       x, Wf, bf_, Wb, bb_, out);
    hipLaunchKernelGGL(rnn_rec, dim3(32), dim3(256), 0, stream,
                       Uf, Ub, out, (unsigned char*)d_ws);
}